// Round 15
// baseline (319.310 us; speedup 1.0000x reference)
//
#include <hip/hip_runtime.h>
#include <math.h>

#define D_    2048
#define QH_   32
#define KVH_  8
#define HD_   64
#define B_    2
#define S_    2048
#define NROW_ (B_*S_)     // 4096
#define KVD_  (KVH_*HD_)  // 512
#define LOG2E 1.44269504f

typedef __bf16 bf16;
typedef __bf16 bf16x2 __attribute__((ext_vector_type(2)));
typedef __bf16 bf16x8 __attribute__((ext_vector_type(8)));
typedef float  f32x4  __attribute__((ext_vector_type(4)));
typedef float  f32x16 __attribute__((ext_vector_type(16)));

__device__ __forceinline__ f32x4 mfma16(bf16x8 a, bf16x8 b, f32x4 c) {
  return __builtin_amdgcn_mfma_f32_16x16x32_bf16(a, b, c, 0, 0, 0);
}
__device__ __forceinline__ f32x16 mfma32(bf16x8 a, bf16x8 b, f32x16 c) {
  return __builtin_amdgcn_mfma_f32_32x32x16_bf16(a, b, c, 0, 0, 0);
}

__device__ __forceinline__ void gload_lds16(const bf16* g, bf16* l) {
  __builtin_amdgcn_global_load_lds(
      (const __attribute__((address_space(1))) void*)g,
      (__attribute__((address_space(3))) void*)l, 16, 0, 0);
}

__device__ __forceinline__ unsigned pack_bf16(float a, float b) {
  union { bf16x2 v; unsigned u; } t;
  t.v[0] = (bf16)a; t.v[1] = (bf16)b;
  return t.u;
}

// ---------------- weight transpose body (W[K][N] f32 -> Wt[N][K] bf16) -------
__device__ __forceinline__ void transpose_w_body(const float* W, bf16* Wt, int K, int N) {
  __shared__ float tile[32][33];
  int n0 = blockIdx.x * 32, k0 = blockIdx.y * 32;
  int tx = threadIdx.x, ty = threadIdx.y;  // (32,8)
#pragma unroll
  for (int j = 0; j < 4; j++)
    tile[ty + 8*j][tx] = W[(size_t)(k0 + ty + 8*j) * N + n0 + tx];
  __syncthreads();
#pragma unroll
  for (int j = 0; j < 4; j++)
    Wt[(size_t)(n0 + ty + 8*j) * K + k0 + tx] = (bf16)tile[tx][ty + 8*j];
}

// ---------------- prep: all 4 weight transposes + rope table, one dispatch ---
// grid (64, 64, 4), block (32,8).
// z=0: Wq (x<64,y<64)     z=1: x<16 Wk; x in[16,32) & y<16 ropetab
// z=2: x<16 Wv            z=3: Wo
__global__ void k_prep(const float* __restrict__ Wq, const float* __restrict__ Wk,
                       const float* __restrict__ Wv, const float* __restrict__ Wo,
                       bf16* __restrict__ WtQ, bf16* __restrict__ WtK,
                       bf16* __restrict__ WtV, bf16* __restrict__ WtO,
                       float2* __restrict__ tab) {
  int z = blockIdx.z, x = blockIdx.x, y = blockIdx.y;
  if (z == 0) {
    transpose_w_body(Wq, WtQ, D_, D_);
  } else if (z == 1) {
    if (x < 16) transpose_w_body(Wk, WtK, D_, KVD_);
    else if (x < 32 && y < 16) {
      int r = (x - 16) * 16 + y;                 // 0..255
      int idx = r * 256 + threadIdx.y * 32 + threadIdx.x;
      int s = idx >> 5, d = idx & 31;
      float invf = exp2f(-(float)d * 0.62286151f);
      float sn, cs;
      sincosf((float)s * invf, &sn, &cs);
      tab[idx] = make_float2(cs, sn);
    }
  } else if (z == 2) {
    if (x < 16) transpose_w_body(Wv, WtV, D_, KVD_);
  } else {
    transpose_w_body(Wo, WtO, D_, D_);
  }
}

// ---------------- Q-proj body: fp32 A reg-staged (fused convert) + RoPE ------
__device__ __forceinline__ void qproj_body(bf16* Asb, bf16* Bsb,
                                           const float* Af, const bf16* Bt,
                                           bf16* C, const float2* tab) {
  const int N = D_, K = D_;
  int tid = threadIdx.x;
  int wave = tid >> 6, lane = tid & 63, hi = lane >> 4, lr = lane & 15;
  int wm = wave >> 1, wn = wave & 1;
  int m0 = blockIdx.y * 128, n0 = blockIdx.x * 128;
  f32x4 acc[4][4] = {};
  const int nk = K >> 6;

  int s_row[4], s_dch[4];
#pragma unroll
  for (int i = 0; i < 4; i++) {
    int c = i * 256 + tid;
    s_row[i] = c >> 3;
    s_dch[i] = (c & 7) ^ (s_row[i] & 7);
  }

  f32x4 areg[4][2];

#define A_LOADQ(kt_)                                                           \
  do {                                                                         \
    int k0_ = (kt_) * 64;                                                      \
    _Pragma("unroll")                                                          \
    for (int i = 0; i < 4; i++) {                                              \
      const float* p = Af + (size_t)(m0 + s_row[i]) * K + k0_ + s_dch[i] * 8;  \
      areg[i][0] = *(const f32x4*)p;                                           \
      areg[i][1] = *(const f32x4*)(p + 4);                                     \
    }                                                                          \
  } while (0)

#define A_WRITEQ(buf)                                                          \
  do {                                                                         \
    _Pragma("unroll")                                                          \
    for (int i = 0; i < 4; i++) {                                              \
      bf16x8 v;                                                                \
      _Pragma("unroll")                                                        \
      for (int j = 0; j < 4; j++) {                                            \
        v[j]     = (bf16)areg[i][0][j];                                        \
        v[4 + j] = (bf16)areg[i][1][j];                                        \
      }                                                                        \
      *(bf16x8*)(Asb + (buf) * 8192 + (i * 256 + tid) * 8) = v;                \
    }                                                                          \
  } while (0)

#define GSTAGE_BQ(buf, kt_)                                                    \
  do {                                                                         \
    int k0_ = (kt_) * 64;                                                      \
    _Pragma("unroll")                                                          \
    for (int i = 0; i < 4; i++)                                                \
      gload_lds16(Bt + (size_t)(n0 + s_row[i]) * K + k0_ + s_dch[i] * 8,       \
                  Bsb + ((buf) * 8192 + (i * 256 + wave * 64) * 8));           \
  } while (0)

  A_LOADQ(0);
  GSTAGE_BQ(0, 0);
  A_WRITEQ(0);
  __syncthreads();

  for (int kt = 0; kt < nk; kt++) {
    int cur = kt & 1;
    if (kt + 1 < nk) {
      A_LOADQ(kt + 1);
      GSTAGE_BQ(cur ^ 1, kt + 1);
    }
#pragma unroll
    for (int kk = 0; kk < 2; kk++) {
      bf16x8 af[4], bfr[4];
#pragma unroll
      for (int mt = 0; mt < 4; mt++) {
        int row = wm * 64 + mt * 16 + lr;
        int sl = (kk * 4 + hi) ^ (row & 7);
        af[mt] = *(const bf16x8*)(Asb + cur * 8192 + row * 64 + sl * 8);
      }
#pragma unroll
      for (int nt = 0; nt < 4; nt++) {
        int row = wn * 64 + nt * 16 + lr;
        int sl = (kk * 4 + hi) ^ (row & 7);
        bfr[nt] = *(const bf16x8*)(Bsb + cur * 8192 + row * 64 + sl * 8);
      }
      __builtin_amdgcn_s_setprio(1);
#pragma unroll
      for (int mt = 0; mt < 4; mt++)
#pragma unroll
        for (int nt = 0; nt < 4; nt++)
          acc[mt][nt] = mfma16(af[mt], bfr[nt], acc[mt][nt]);
      __builtin_amdgcn_s_setprio(0);
    }
    if (kt + 1 < nk) A_WRITEQ(cur ^ 1);
    __syncthreads();
  }
#undef A_LOADQ
#undef A_WRITEQ
#undef GSTAGE_BQ

#pragma unroll
  for (int mt = 0; mt < 4; mt++)
#pragma unroll
    for (int r = 0; r < 4; r++) {
      int grow = m0 + wm * 64 + mt * 16 + 4 * hi + r;
      int s = grow & (S_ - 1);
#pragma unroll
      for (int nt = 0; nt < 2; nt++) {
        int gcol = n0 + wn * 64 + nt * 16 + lr;
        float2 cs = tab[s * 32 + nt * 16 + lr];
        float x1 = acc[mt][nt][r], x2 = acc[mt][nt + 2][r];
        C[(size_t)grow * N + gcol]      = (bf16)(x1 * cs.x - x2 * cs.y);
        C[(size_t)grow * N + gcol + 32] = (bf16)(x2 * cs.x + x1 * cs.y);
      }
    }
}

// ---------------- KV GEMM body: 64x128 tile, fused fp32->bf16 A-staging ------
// EPI: 1 = RoPE K out   3 = transposed V store (swapped mfma operands)
template<int EPI>
__device__ __forceinline__ void gemm_body64(bf16* Asb, bf16* Bsb,
                                            const float* Af, const bf16* Bt, void* Cout,
                                            const float2* tab) {
  const int K = D_, N = KVD_;
  int tid = threadIdx.x;
  int wave = tid >> 6, lane = tid & 63, hi = lane >> 4, lr = lane & 15;
  int m0 = blockIdx.y * 64, n0 = blockIdx.x * 128;
  int nbase = (wave >> 1) * 64 + (wave & 1) * 16;   // + nt*32
  f32x4 acc[4][2] = {};
  const int nk = K >> 6;

  int a_row[2], a_dch[2], b_row[4], b_dch[4];
#pragma unroll
  for (int i = 0; i < 2; i++) {
    int c = i * 256 + tid;
    a_row[i] = c >> 3;
    a_dch[i] = (c & 7) ^ (a_row[i] & 7);
  }
#pragma unroll
  for (int i = 0; i < 4; i++) {
    int c = i * 256 + tid;
    b_row[i] = c >> 3;
    b_dch[i] = (c & 7) ^ (b_row[i] & 7);
  }

  f32x4 areg[2][2];

#define A_LOAD(kt_)                                                            \
  do {                                                                         \
    int k0_ = (kt_) * 64;                                                      \
    _Pragma("unroll")                                                          \
    for (int i = 0; i < 2; i++) {                                              \
      const float* p = Af + (size_t)(m0 + a_row[i]) * K + k0_ + a_dch[i] * 8;  \
      areg[i][0] = *(const f32x4*)p;                                           \
      areg[i][1] = *(const f32x4*)(p + 4);                                     \
    }                                                                          \
  } while (0)

#define A_WRITE(buf)                                                           \
  do {                                                                         \
    _Pragma("unroll")                                                          \
    for (int i = 0; i < 2; i++) {                                              \
      bf16x8 v;                                                                \
      _Pragma("unroll")                                                        \
      for (int j = 0; j < 4; j++) {                                            \
        v[j]     = (bf16)areg[i][0][j];                                        \
        v[4 + j] = (bf16)areg[i][1][j];                                        \
      }                                                                        \
      *(bf16x8*)(Asb + (buf) * 4096 + (i * 256 + tid) * 8) = v;                \
    }                                                                          \
  } while (0)

#define GSTAGE_B(buf, kt_)                                                     \
  do {                                                                         \
    int k0_ = (kt_) * 64;                                                      \
    _Pragma("unroll")                                                          \
    for (int i = 0; i < 4; i++)                                                \
      gload_lds16(Bt + (size_t)(n0 + b_row[i]) * K + k0_ + b_dch[i] * 8,       \
                  Bsb + ((buf) * 8192 + (i * 256 + wave * 64) * 8));           \
  } while (0)

  A_LOAD(0);
  GSTAGE_B(0, 0);
  A_WRITE(0);
  __syncthreads();

  for (int kt = 0; kt < nk; kt++) {
    int cur = kt & 1;
    if (kt + 1 < nk) {
      A_LOAD(kt + 1);
      GSTAGE_B(cur ^ 1, kt + 1);
    }
#pragma unroll
    for (int kk = 0; kk < 2; kk++) {
      bf16x8 af[4], bfr[2];
#pragma unroll
      for (int mt = 0; mt < 4; mt++) {
        int row = mt * 16 + lr;
        int sl = (kk * 4 + hi) ^ (row & 7);
        af[mt] = *(const bf16x8*)(Asb + cur * 4096 + row * 64 + sl * 8);
      }
#pragma unroll
      for (int nt = 0; nt < 2; nt++) {
        int row = nbase + nt * 32 + lr;
        int sl = (kk * 4 + hi) ^ (row & 7);
        bfr[nt] = *(const bf16x8*)(Bsb + cur * 8192 + row * 64 + sl * 8);
      }
      __builtin_amdgcn_s_setprio(1);
#pragma unroll
      for (int mt = 0; mt < 4; mt++)
#pragma unroll
        for (int nt = 0; nt < 2; nt++) {
          if (EPI == 3) acc[mt][nt] = mfma16(bfr[nt], af[mt], acc[mt][nt]);
          else          acc[mt][nt] = mfma16(af[mt], bfr[nt], acc[mt][nt]);
        }
      __builtin_amdgcn_s_setprio(0);
    }
    if (kt + 1 < nk) A_WRITE(cur ^ 1);
    __syncthreads();
  }
#undef A_LOAD
#undef A_WRITE
#undef GSTAGE_B

  if (EPI == 1) {
#pragma unroll
    for (int mt = 0; mt < 4; mt++)
#pragma unroll
      for (int r = 0; r < 4; r++) {
        int grow = m0 + mt * 16 + 4 * hi + r;
        int s = grow & (S_ - 1);
        int d = (wave & 1) * 16 + lr;
        int gcol = n0 + nbase + lr;
        float2 cs = tab[s * 32 + d];
        float x1 = acc[mt][0][r], x2 = acc[mt][1][r];
        ((bf16*)Cout)[(size_t)grow * N + gcol]      = (bf16)(x1 * cs.x - x2 * cs.y);
        ((bf16*)Cout)[(size_t)grow * N + gcol + 32] = (bf16)(x2 * cs.x + x1 * cs.y);
      }
  } else {
    int b = m0 >> 11;
#pragma unroll
    for (int mt = 0; mt < 4; mt++)
#pragma unroll
      for (int nt = 0; nt < 2; nt++)
#pragma unroll
        for (int r = 0; r < 4; r++) {
          int n = n0 + nbase + nt * 32 + 4 * hi + r;
          int m = m0 + mt * 16 + lr;
          ((bf16*)Cout)[((size_t)(b * KVD_ + n)) * S_ + (m & (S_ - 1))] =
              (bf16)acc[mt][nt][r];
        }
  }
}

// ---------------- merged Q + K + V projection dispatch ----------------
// grid (16, 64, 3): z=0 Q (y<32), z=1 K (x<4), z=2 V (x<4); else exit.
__global__ __launch_bounds__(256) void k_gemm_qkv(const float* __restrict__ q,
                                                  const float* __restrict__ k,
                                                  const float* __restrict__ v,
                                                  const bf16* __restrict__ WtQ,
                                                  const bf16* __restrict__ WtK,
                                                  const bf16* __restrict__ WtV,
                                                  bf16* __restrict__ Qh,
                                                  bf16* __restrict__ Kh,
                                                  bf16* __restrict__ Vt,
                                                  const float2* __restrict__ tab) {
  __shared__ alignas(16) bf16 As[2][128 * 64];
  __shared__ alignas(16) bf16 Bs[2][128 * 64];
  int z = blockIdx.z;
  if (z == 0) {
    if (blockIdx.y >= 32) return;
    qproj_body(&As[0][0], &Bs[0][0], q, WtQ, Qh, tab);
  } else if (z == 1) {
    if (blockIdx.x >= 4) return;
    gemm_body64<1>(&As[0][0], &Bs[0][0], k, WtK, Kh, tab);
  } else {
    if (blockIdx.x >= 4) return;
    gemm_body64<3>(&As[0][0], &Bs[0][0], v, WtV, Vt, nullptr);
  }
}

// ---------------- O-proj GEMM (bf16 A, +bias, fp32 out) ----------------
__global__ __launch_bounds__(256) void k_gemm_o(const bf16* __restrict__ A,
                                                const bf16* __restrict__ Bt,
                                                float* __restrict__ C,
                                                const float* __restrict__ bias) {
  __shared__ alignas(16) bf16 As[2][128 * 64];
  __shared__ alignas(16) bf16 Bs[2][128 * 64];
  bf16* Asb = &As[0][0];
  bf16* Bsb = &Bs[0][0];
  const int N = D_, K = D_;
  int tid = threadIdx.x;
  int wave = tid >> 6, lane = tid & 63, hi = lane >> 4, lr = lane & 15;
  int wm = wave >> 1, wn = wave & 1;
  int m0 = blockIdx.y * 128, n0 = blockIdx.x * 128;
  f32x4 acc[4][4] = {};
  const int nk = K >> 6;

  int s_row[4], s_dch[4];
#pragma unroll
  for (int i = 0; i < 4; i++) {
    int c = i * 256 + tid;
    s_row[i] = c >> 3;
    s_dch[i] = (c & 7) ^ (s_row[i] & 7);
  }

#define GSTAGE(buf, kt_)                                                       \
  do {                                                                         \
    int k0_ = (kt_) * 64;                                                      \
    _Pragma("unroll")                                                          \
    for (int i = 0; i < 4; i++) {                                              \
      gload_lds16(A  + (size_t)(m0 + s_row[i]) * K + k0_ + s_dch[i] * 8,       \
                  Asb + ((buf) * 8192 + (i * 256 + wave * 64) * 8));           \
      gload_lds16(Bt + (size_t)(n0 + s_row[i]) * K + k0_ + s_dch[i] * 8,       \
                  Bsb + ((buf) * 8192 + (i * 256 + wave * 64) * 8));           \
    }                                                                          \
  } while (0)

  GSTAGE(0, 0);
  __syncthreads();

  for (int kt = 0; kt < nk; kt++) {
    int cur = kt & 1;
    if (kt + 1 < nk) GSTAGE(cur ^ 1, kt + 1);
#pragma unroll
    for (int kk = 0; kk < 2; kk++) {
      bf16x8 af[4], bfr[4];
#pragma unroll
      for (int mt = 0; mt < 4; mt++) {
        int row = wm * 64 + mt * 16 + lr;
        int sl = (kk * 4 + hi) ^ (row & 7);
        af[mt] = *(const bf16x8*)(Asb + cur * 8192 + row * 64 + sl * 8);
      }
#pragma unroll
      for (int nt = 0; nt < 4; nt++) {
        int row = wn * 64 + nt * 16 + lr;
        int sl = (kk * 4 + hi) ^ (row & 7);
        bfr[nt] = *(const bf16x8*)(Bsb + cur * 8192 + row * 64 + sl * 8);
      }
      __builtin_amdgcn_s_setprio(1);
#pragma unroll
      for (int mt = 0; mt < 4; mt++)
#pragma unroll
        for (int nt = 0; nt < 4; nt++)
          acc[mt][nt] = mfma16(af[mt], bfr[nt], acc[mt][nt]);
      __builtin_amdgcn_s_setprio(0);
    }
    __syncthreads();
  }
#undef GSTAGE

#pragma unroll
  for (int mt = 0; mt < 4; mt++)
#pragma unroll
    for (int nt = 0; nt < 4; nt++)
#pragma unroll
      for (int r = 0; r < 4; r++) {
        int grow = m0 + wm * 64 + mt * 16 + 4 * hi + r;
        int gcol = n0 + wn * 64 + nt * 16 + lr;
        C[(size_t)grow * N + gcol] = acc[mt][nt][r] + bias[gcol];
      }
}

// ---------------- Flash attention v4 (accl restored — proven 81.3 us) --------
__global__ __launch_bounds__(512, 4) void k_attn(const bf16* __restrict__ Qh,
                                                 const bf16* __restrict__ Kh,
                                                 const bf16* __restrict__ Vt,
                                                 bf16* __restrict__ ctx) {
  __shared__ alignas(16) bf16 Ks[2][64 * 64];
  __shared__ alignas(16) bf16 Vs[2][64 * 64];
  int tid = threadIdx.x;
  int wave = tid >> 6, lane = tid & 63, hi2 = lane >> 5, l31 = lane & 31;
  int qt = blockIdx.x, h = blockIdx.y, b = blockIdx.z;
  int kv = h & 7;
  int q0 = qt * 256 + wave * 32;

  bf16x8 qf[4];
  {
    const float QSC = 0.125f * LOG2E;
    const bf16* qp = Qh + (size_t)(b * S_ + q0 + l31) * D_ + h * HD_ + hi2 * 8;
#pragma unroll
    for (int df = 0; df < 4; df++) {
      bf16x8 v = *(const bf16x8*)(qp + 16 * df);
#pragma unroll
      for (int j = 0; j < 8; j++) v[j] = (bf16)((float)v[j] * QSC);
      qf[df] = v;
    }
  }

  f32x16 o0, o1, accl;
#pragma unroll
  for (int i = 0; i < 16; i++) { o0[i] = 0.f; o1[i] = 0.f; accl[i] = 0.f; }
  bf16x8 ones;
#pragma unroll
  for (int j = 0; j < 8; j++) ones[j] = (bf16)1.0f;

  const bf16* Kg = Kh + (size_t)(b * S_) * KVD_ + kv * HD_;
  const bf16* Vg = Vt + (size_t)(b * KVH_ + kv) * HD_ * S_;

  int c_row = tid >> 3, c_slot = tid & 7;
  int c_dch = c_slot ^ (c_row & 7);

#define STAGE(buf, kt_)                                                        \
  do {                                                                         \
    gload_lds16(Kg + (size_t)((kt_) * 64 + c_row) * KVD_ + c_dch * 8,          \
                &Ks[buf][tid * 8]);                                            \
    gload_lds16(Vg + (size_t)c_row * S_ + (kt_) * 64 + c_dch * 8,              \
                &Vs[buf][tid * 8]);                                            \
  } while (0)

  STAGE(0, 0);
  __syncthreads();

  const int NT = S_ / 64;
  for (int kt = 0; kt < NT; kt++) {
    int cur = kt & 1;
    if (kt + 1 < NT) STAGE(cur ^ 1, kt + 1);

    const bf16* Kb = &Ks[cur][0];
    const bf16* Vb = &Vs[cur][0];

    f32x16 s0, s1;
#pragma unroll
    for (int i = 0; i < 16; i++) { s0[i] = 0.f; s1[i] = 0.f; }
    __builtin_amdgcn_s_setprio(1);
#pragma unroll
    for (int df = 0; df < 4; df++) {
      int ch = hi2 + 2 * df;
      int sl = (ch ^ (l31 & 7)) << 3;
      bf16x8 k0 = *(const bf16x8*)(Kb + l31 * 64 + sl);
      bf16x8 k1 = *(const bf16x8*)(Kb + (l31 + 32) * 64 + sl);
      s0 = mfma32(k0, qf[df], s0);
      s1 = mfma32(k1, qf[df], s1);
    }
    __builtin_amdgcn_s_setprio(0);

#pragma unroll
    for (int i = 0; i < 16; i++) s0[i] = __builtin_amdgcn_exp2f(s0[i]);
#pragma unroll
    for (int i = 0; i < 16; i++) s1[i] = __builtin_amdgcn_exp2f(s1[i]);

    unsigned Rk[2][4][2];
#pragma unroll
    for (int m = 0; m < 4; m++)
#pragma unroll
      for (int w = 0; w < 2; w++) {
        Rk[0][m][w] = pack_bf16(s0[4*m + 2*w], s0[4*m + 2*w + 1]);
        Rk[1][m][w] = pack_bf16(s1[4*m + 2*w], s1[4*m + 2*w + 1]);
      }
#pragma unroll
    for (int kf = 0; kf < 2; kf++)
#pragma unroll
      for (int kp = 0; kp < 2; kp++)
#pragma unroll
        for (int w = 0; w < 2; w++)
          asm volatile("v_permlane32_swap_b32 %0, %1"
                       : "+v"(Rk[kf][2*kp][w]), "+v"(Rk[kf][2*kp+1][w]));
    bf16x8 pf[4];
#pragma unroll
    for (int kfr = 0; kfr < 4; kfr++) {
      int kf = kfr >> 1, k2 = (kfr & 1) * 2;
      union { unsigned d[4]; bf16x8 v; } u;
      u.d[0] = Rk[kf][k2][0];     u.d[1] = Rk[kf][k2][1];
      u.d[2] = Rk[kf][k2 + 1][0]; u.d[3] = Rk[kf][k2 + 1][1];
      pf[kfr] = u.v;
    }

    __builtin_amdgcn_s_setprio(1);
#pragma unroll
    for (int kfr = 0; kfr < 4; kfr++) {
      int ch = hi2 + 2 * kfr;
      int sl = (ch ^ (l31 & 7)) << 3;
      bf16x8 v0 = *(const bf16x8*)(Vb + l31 * 64 + sl);
      bf16x8 v1 = *(const bf16x8*)(Vb + (l31 + 32) * 64 + sl);
      o0 = mfma32(pf[kfr], v0, o0);
      o1 = mfma32(pf[kfr], v1, o1);
      accl = mfma32(pf[kfr], ones, accl);
    }
    __builtin_amdgcn_s_setprio(0);
    __syncthreads();
  }
#undef STAGE

#pragma unroll
  for (int r = 0; r < 16; r++) {
    int rowq = (r & 3) + 8 * (r >> 2) + 4 * hi2;
    float inv = 1.f / accl[r];
    size_t base = (size_t)(b * S_ + q0 + rowq) * D_ + h * HD_;
    ctx[base + l31]      = (bf16)(o0[r] * inv);
    ctx[base + l31 + 32] = (bf16)(o1[r] * inv);
  }
}

// ---------------- host: 4 dispatches ----------------
extern "C" void kernel_launch(void* const* d_in, const int* in_sizes, int n_in,
                              void* d_out, int out_size, void* d_ws, size_t ws_size,
                              hipStream_t stream) {
  const float* q  = (const float*)d_in[0];
  const float* k  = (const float*)d_in[1];
  const float* v  = (const float*)d_in[2];
  const float* Wq = (const float*)d_in[4];
  const float* Wk = (const float*)d_in[5];
  const float* Wv = (const float*)d_in[6];
  const float* Wo = (const float*)d_in[7];
  const float* bo = (const float*)d_in[8];

  char* ws = (char*)d_ws;
  bf16*   WtO = (bf16*)(ws + 0);           //  8.39 MB
  bf16*   WtK = (bf16*)(ws + 8388608);     //  2.10 MB
  bf16*   WtV = (bf16*)(ws + 10485760);    //  2.10 MB
  bf16*   ctx = (bf16*)(ws + 16777216);    // 16.78 MB
  bf16*   WtQ = (bf16*)(ws + 33554432);    //  8.39 MB
  bf16*   Qh  = (bf16*)(ws + 41943040);    // 16.78 MB
  bf16*   Kh  = (bf16*)(ws + 58720256);    //  4.19 MB
  bf16*   Vt  = (bf16*)(ws + 62914560);    //  4.19 MB  [B][KVD][S]
  float2* tab = (float2*)(ws + 67108864);  //  0.52 MB  (end 67,633,152)

  k_prep<<<dim3(64, 64, 4), dim3(32, 8), 0, stream>>>(Wq, Wk, Wv, Wo,
                                                      WtQ, WtK, WtV, WtO, tab);
  k_gemm_qkv<<<dim3(16, 64, 3), 256, 0, stream>>>(q, k, v, WtQ, WtK, WtV,
                                                  Qh, Kh, Vt, tab);
  k_attn<<<dim3(S_/256, QH_, B_), 512, 0, stream>>>(Qh, Kh, Vt, ctx);
  k_gemm_o<<<dim3(D_/128, NROW_/128), 256, 0, stream>>>(ctx, WtO, (float*)d_out, bo);
}

// Round 16
// 230.747 us; speedup vs baseline: 1.3838x; 1.3838x over previous
//
#include <hip/hip_runtime.h>
#include <math.h>

#define D_    2048
#define QH_   32
#define KVH_  8
#define HD_   64
#define B_    2
#define S_    2048
#define NROW_ (B_*S_)     // 4096
#define KVD_  (KVH_*HD_)  // 512
#define LOG2E 1.44269504f

typedef __bf16 bf16;
typedef __bf16 bf16x2 __attribute__((ext_vector_type(2)));
typedef __bf16 bf16x8 __attribute__((ext_vector_type(8)));
typedef float  f32x4  __attribute__((ext_vector_type(4)));
typedef float  f32x16 __attribute__((ext_vector_type(16)));

__device__ __forceinline__ f32x4 mfma16(bf16x8 a, bf16x8 b, f32x4 c) {
  return __builtin_amdgcn_mfma_f32_16x16x32_bf16(a, b, c, 0, 0, 0);
}
__device__ __forceinline__ f32x16 mfma32(bf16x8 a, bf16x8 b, f32x16 c) {
  return __builtin_amdgcn_mfma_f32_32x32x16_bf16(a, b, c, 0, 0, 0);
}

__device__ __forceinline__ void gload_lds16(const bf16* g, bf16* l) {
  __builtin_amdgcn_global_load_lds(
      (const __attribute__((address_space(1))) void*)g,
      (__attribute__((address_space(3))) void*)l, 16, 0, 0);
}

__device__ __forceinline__ unsigned pack_bf16(float a, float b) {
  union { bf16x2 v; unsigned u; } t;
  t.v[0] = (bf16)a; t.v[1] = (bf16)b;
  return t.u;
}

// ---------------- weight transpose body (W[K][N] f32 -> Wt[N][K] bf16) -------
__device__ __forceinline__ void transpose_w_body(const float* W, bf16* Wt, int K, int N) {
  __shared__ float tile[32][33];
  int n0 = blockIdx.x * 32, k0 = blockIdx.y * 32;
  int tx = threadIdx.x, ty = threadIdx.y;  // (32,8)
#pragma unroll
  for (int j = 0; j < 4; j++)
    tile[ty + 8*j][tx] = W[(size_t)(k0 + ty + 8*j) * N + n0 + tx];
  __syncthreads();
#pragma unroll
  for (int j = 0; j < 4; j++)
    Wt[(size_t)(n0 + ty + 8*j) * K + k0 + tx] = (bf16)tile[tx][ty + 8*j];
}

// ---------------- prep: all 4 weight transposes + rope table, one dispatch ---
__global__ void k_prep(const float* __restrict__ Wq, const float* __restrict__ Wk,
                       const float* __restrict__ Wv, const float* __restrict__ Wo,
                       bf16* __restrict__ WtQ, bf16* __restrict__ WtK,
                       bf16* __restrict__ WtV, bf16* __restrict__ WtO,
                       float2* __restrict__ tab) {
  int z = blockIdx.z, x = blockIdx.x, y = blockIdx.y;
  if (z == 0) {
    transpose_w_body(Wq, WtQ, D_, D_);
  } else if (z == 1) {
    if (x < 16) transpose_w_body(Wk, WtK, D_, KVD_);
    else if (x < 32 && y < 16) {
      int r = (x - 16) * 16 + y;                 // 0..255
      int idx = r * 256 + threadIdx.y * 32 + threadIdx.x;
      int s = idx >> 5, d = idx & 31;
      float invf = exp2f(-(float)d * 0.62286151f);
      float sn, cs;
      sincosf((float)s * invf, &sn, &cs);
      tab[idx] = make_float2(cs, sn);
    }
  } else if (z == 2) {
    if (x < 16) transpose_w_body(Wv, WtV, D_, KVD_);
  } else {
    transpose_w_body(Wo, WtO, D_, D_);
  }
}

// ---------------- Q-proj GEMM: fp32 A reg-staged (fused convert) + RoPE ------
__global__ __launch_bounds__(256) void k_gemm_q(const float* __restrict__ Af,
                                                const bf16* __restrict__ Bt,
                                                bf16* __restrict__ C,
                                                const float2* __restrict__ tab) {
  __shared__ alignas(16) bf16 As[2][128 * 64];
  __shared__ alignas(16) bf16 Bs[2][128 * 64];
  bf16* Asb = &As[0][0];
  bf16* Bsb = &Bs[0][0];
  const int N = D_, K = D_;
  int tid = threadIdx.x;
  int wave = tid >> 6, lane = tid & 63, hi = lane >> 4, lr = lane & 15;
  int wm = wave >> 1, wn = wave & 1;
  int m0 = blockIdx.y * 128, n0 = blockIdx.x * 128;
  f32x4 acc[4][4] = {};
  const int nk = K >> 6;

  int s_row[4], s_dch[4];
#pragma unroll
  for (int i = 0; i < 4; i++) {
    int c = i * 256 + tid;
    s_row[i] = c >> 3;
    s_dch[i] = (c & 7) ^ (s_row[i] & 7);
  }

  f32x4 areg[4][2];

#define A_LOADQ(kt_)                                                           \
  do {                                                                         \
    int k0_ = (kt_) * 64;                                                      \
    _Pragma("unroll")                                                          \
    for (int i = 0; i < 4; i++) {                                              \
      const float* p = Af + (size_t)(m0 + s_row[i]) * K + k0_ + s_dch[i] * 8;  \
      areg[i][0] = *(const f32x4*)p;                                           \
      areg[i][1] = *(const f32x4*)(p + 4);                                     \
    }                                                                          \
  } while (0)

#define A_WRITEQ(buf)                                                          \
  do {                                                                         \
    _Pragma("unroll")                                                          \
    for (int i = 0; i < 4; i++) {                                              \
      bf16x8 v;                                                                \
      _Pragma("unroll")                                                        \
      for (int j = 0; j < 4; j++) {                                            \
        v[j]     = (bf16)areg[i][0][j];                                        \
        v[4 + j] = (bf16)areg[i][1][j];                                        \
      }                                                                        \
      *(bf16x8*)(Asb + (buf) * 8192 + (i * 256 + tid) * 8) = v;                \
    }                                                                          \
  } while (0)

#define GSTAGE_BQ(buf, kt_)                                                    \
  do {                                                                         \
    int k0_ = (kt_) * 64;                                                      \
    _Pragma("unroll")                                                          \
    for (int i = 0; i < 4; i++)                                                \
      gload_lds16(Bt + (size_t)(n0 + s_row[i]) * K + k0_ + s_dch[i] * 8,       \
                  Bsb + ((buf) * 8192 + (i * 256 + wave * 64) * 8));           \
  } while (0)

  A_LOADQ(0);
  GSTAGE_BQ(0, 0);
  A_WRITEQ(0);
  __syncthreads();

  for (int kt = 0; kt < nk; kt++) {
    int cur = kt & 1;
    if (kt + 1 < nk) {
      A_LOADQ(kt + 1);
      GSTAGE_BQ(cur ^ 1, kt + 1);
    }
#pragma unroll
    for (int kk = 0; kk < 2; kk++) {
      bf16x8 af[4], bfr[4];
#pragma unroll
      for (int mt = 0; mt < 4; mt++) {
        int row = wm * 64 + mt * 16 + lr;
        int sl = (kk * 4 + hi) ^ (row & 7);
        af[mt] = *(const bf16x8*)(Asb + cur * 8192 + row * 64 + sl * 8);
      }
#pragma unroll
      for (int nt = 0; nt < 4; nt++) {
        int row = wn * 64 + nt * 16 + lr;
        int sl = (kk * 4 + hi) ^ (row & 7);
        bfr[nt] = *(const bf16x8*)(Bsb + cur * 8192 + row * 64 + sl * 8);
      }
      __builtin_amdgcn_s_setprio(1);
#pragma unroll
      for (int mt = 0; mt < 4; mt++)
#pragma unroll
        for (int nt = 0; nt < 4; nt++)
          acc[mt][nt] = mfma16(af[mt], bfr[nt], acc[mt][nt]);
      __builtin_amdgcn_s_setprio(0);
    }
    if (kt + 1 < nk) A_WRITEQ(cur ^ 1);
    __syncthreads();
  }
#undef A_LOADQ
#undef A_WRITEQ
#undef GSTAGE_BQ

  // RoPE epilogue: pair (d, d+32) = (nt, nt+2); d = nt*16+lr < 32
#pragma unroll
  for (int mt = 0; mt < 4; mt++)
#pragma unroll
    for (int r = 0; r < 4; r++) {
      int grow = m0 + wm * 64 + mt * 16 + 4 * hi + r;
      int s = grow & (S_ - 1);
#pragma unroll
      for (int nt = 0; nt < 2; nt++) {
        int gcol = n0 + wn * 64 + nt * 16 + lr;
        float2 cs = tab[s * 32 + nt * 16 + lr];
        float x1 = acc[mt][nt][r], x2 = acc[mt][nt + 2][r];
        C[(size_t)grow * N + gcol]      = (bf16)(x1 * cs.x - x2 * cs.y);
        C[(size_t)grow * N + gcol + 32] = (bf16)(x2 * cs.x + x1 * cs.y);
      }
    }
}

// ---------------- KV GEMM: 64x128 tile, fused fp32->bf16 A-staging -----------
// EPI: 1 = RoPE K out   3 = transposed V store (swapped mfma operands)
template<int EPI>
__device__ __forceinline__ void gemm_body64(bf16* Asb, bf16* Bsb,
                                            const float* Af, const bf16* Bt, void* Cout,
                                            const float2* tab) {
  const int K = D_, N = KVD_;
  int tid = threadIdx.x;
  int wave = tid >> 6, lane = tid & 63, hi = lane >> 4, lr = lane & 15;
  int m0 = blockIdx.y * 64, n0 = blockIdx.x * 128;
  int nbase = (wave >> 1) * 64 + (wave & 1) * 16;   // + nt*32
  f32x4 acc[4][2] = {};
  const int nk = K >> 6;

  int a_row[2], a_dch[2], b_row[4], b_dch[4];
#pragma unroll
  for (int i = 0; i < 2; i++) {
    int c = i * 256 + tid;
    a_row[i] = c >> 3;
    a_dch[i] = (c & 7) ^ (a_row[i] & 7);
  }
#pragma unroll
  for (int i = 0; i < 4; i++) {
    int c = i * 256 + tid;
    b_row[i] = c >> 3;
    b_dch[i] = (c & 7) ^ (b_row[i] & 7);
  }

  f32x4 areg[2][2];

#define A_LOAD(kt_)                                                            \
  do {                                                                         \
    int k0_ = (kt_) * 64;                                                      \
    _Pragma("unroll")                                                          \
    for (int i = 0; i < 2; i++) {                                              \
      const float* p = Af + (size_t)(m0 + a_row[i]) * K + k0_ + a_dch[i] * 8;  \
      areg[i][0] = *(const f32x4*)p;                                           \
      areg[i][1] = *(const f32x4*)(p + 4);                                     \
    }                                                                          \
  } while (0)

#define A_WRITE(buf)                                                           \
  do {                                                                         \
    _Pragma("unroll")                                                          \
    for (int i = 0; i < 2; i++) {                                              \
      bf16x8 v;                                                                \
      _Pragma("unroll")                                                        \
      for (int j = 0; j < 4; j++) {                                            \
        v[j]     = (bf16)areg[i][0][j];                                        \
        v[4 + j] = (bf16)areg[i][1][j];                                        \
      }                                                                        \
      *(bf16x8*)(Asb + (buf) * 4096 + (i * 256 + tid) * 8) = v;                \
    }                                                                          \
  } while (0)

#define GSTAGE_B(buf, kt_)                                                     \
  do {                                                                         \
    int k0_ = (kt_) * 64;                                                      \
    _Pragma("unroll")                                                          \
    for (int i = 0; i < 4; i++)                                                \
      gload_lds16(Bt + (size_t)(n0 + b_row[i]) * K + k0_ + b_dch[i] * 8,       \
                  Bsb + ((buf) * 8192 + (i * 256 + wave * 64) * 8));           \
  } while (0)

  A_LOAD(0);
  GSTAGE_B(0, 0);
  A_WRITE(0);
  __syncthreads();

  for (int kt = 0; kt < nk; kt++) {
    int cur = kt & 1;
    if (kt + 1 < nk) {
      A_LOAD(kt + 1);
      GSTAGE_B(cur ^ 1, kt + 1);
    }
#pragma unroll
    for (int kk = 0; kk < 2; kk++) {
      bf16x8 af[4], bfr[2];
#pragma unroll
      for (int mt = 0; mt < 4; mt++) {
        int row = mt * 16 + lr;
        int sl = (kk * 4 + hi) ^ (row & 7);
        af[mt] = *(const bf16x8*)(Asb + cur * 4096 + row * 64 + sl * 8);
      }
#pragma unroll
      for (int nt = 0; nt < 2; nt++) {
        int row = nbase + nt * 32 + lr;
        int sl = (kk * 4 + hi) ^ (row & 7);
        bfr[nt] = *(const bf16x8*)(Bsb + cur * 8192 + row * 64 + sl * 8);
      }
      __builtin_amdgcn_s_setprio(1);
#pragma unroll
      for (int mt = 0; mt < 4; mt++)
#pragma unroll
        for (int nt = 0; nt < 2; nt++) {
          if (EPI == 3) acc[mt][nt] = mfma16(bfr[nt], af[mt], acc[mt][nt]);
          else          acc[mt][nt] = mfma16(af[mt], bfr[nt], acc[mt][nt]);
        }
      __builtin_amdgcn_s_setprio(0);
    }
    if (kt + 1 < nk) A_WRITE(cur ^ 1);
    __syncthreads();
  }
#undef A_LOAD
#undef A_WRITE
#undef GSTAGE_B

  if (EPI == 1) {
#pragma unroll
    for (int mt = 0; mt < 4; mt++)
#pragma unroll
      for (int r = 0; r < 4; r++) {
        int grow = m0 + mt * 16 + 4 * hi + r;
        int s = grow & (S_ - 1);
        int d = (wave & 1) * 16 + lr;
        int gcol = n0 + nbase + lr;
        float2 cs = tab[s * 32 + d];
        float x1 = acc[mt][0][r], x2 = acc[mt][1][r];
        ((bf16*)Cout)[(size_t)grow * N + gcol]      = (bf16)(x1 * cs.x - x2 * cs.y);
        ((bf16*)Cout)[(size_t)grow * N + gcol + 32] = (bf16)(x2 * cs.x + x1 * cs.y);
      }
  } else {
    int b = m0 >> 11;
#pragma unroll
    for (int mt = 0; mt < 4; mt++)
#pragma unroll
      for (int nt = 0; nt < 2; nt++)
#pragma unroll
        for (int r = 0; r < 4; r++) {
          int n = n0 + nbase + nt * 32 + 4 * hi + r;
          int m = m0 + mt * 16 + lr;
          ((bf16*)Cout)[((size_t)(b * KVD_ + n)) * S_ + (m & (S_ - 1))] =
              (bf16)acc[mt][nt][r];
        }
  }
}

__global__ __launch_bounds__(256) void k_gemm_kv(const float* __restrict__ kf,
                                                 const float* __restrict__ vf,
                                                 const bf16* __restrict__ B0,
                                                 const bf16* __restrict__ B1,
                                                 bf16* __restrict__ Kh,
                                                 bf16* __restrict__ Vt,
                                                 const float2* __restrict__ tab) {
  __shared__ alignas(16) bf16 As[2][64 * 64];
  __shared__ alignas(16) bf16 Bs[2][128 * 64];
  if (blockIdx.z == 0) gemm_body64<1>(&As[0][0], &Bs[0][0], kf, B0, Kh, tab);
  else                 gemm_body64<3>(&As[0][0], &Bs[0][0], vf, B1, Vt, nullptr);
}

// ---------------- O-proj GEMM (bf16 A, +bias, fp32 out) ----------------
__global__ __launch_bounds__(256) void k_gemm_o(const bf16* __restrict__ A,
                                                const bf16* __restrict__ Bt,
                                                float* __restrict__ C,
                                                const float* __restrict__ bias) {
  __shared__ alignas(16) bf16 As[2][128 * 64];
  __shared__ alignas(16) bf16 Bs[2][128 * 64];
  bf16* Asb = &As[0][0];
  bf16* Bsb = &Bs[0][0];
  const int N = D_, K = D_;
  int tid = threadIdx.x;
  int wave = tid >> 6, lane = tid & 63, hi = lane >> 4, lr = lane & 15;
  int wm = wave >> 1, wn = wave & 1;
  int m0 = blockIdx.y * 128, n0 = blockIdx.x * 128;
  f32x4 acc[4][4] = {};
  const int nk = K >> 6;

  int s_row[4], s_dch[4];
#pragma unroll
  for (int i = 0; i < 4; i++) {
    int c = i * 256 + tid;
    s_row[i] = c >> 3;
    s_dch[i] = (c & 7) ^ (s_row[i] & 7);
  }

#define GSTAGE(buf, kt_)                                                       \
  do {                                                                         \
    int k0_ = (kt_) * 64;                                                      \
    _Pragma("unroll")                                                          \
    for (int i = 0; i < 4; i++) {                                              \
      gload_lds16(A  + (size_t)(m0 + s_row[i]) * K + k0_ + s_dch[i] * 8,       \
                  Asb + ((buf) * 8192 + (i * 256 + wave * 64) * 8));           \
      gload_lds16(Bt + (size_t)(n0 + s_row[i]) * K + k0_ + s_dch[i] * 8,       \
                  Bsb + ((buf) * 8192 + (i * 256 + wave * 64) * 8));           \
    }                                                                          \
  } while (0)

  GSTAGE(0, 0);
  __syncthreads();

  for (int kt = 0; kt < nk; kt++) {
    int cur = kt & 1;
    if (kt + 1 < nk) GSTAGE(cur ^ 1, kt + 1);
#pragma unroll
    for (int kk = 0; kk < 2; kk++) {
      bf16x8 af[4], bfr[4];
#pragma unroll
      for (int mt = 0; mt < 4; mt++) {
        int row = wm * 64 + mt * 16 + lr;
        int sl = (kk * 4 + hi) ^ (row & 7);
        af[mt] = *(const bf16x8*)(Asb + cur * 8192 + row * 64 + sl * 8);
      }
#pragma unroll
      for (int nt = 0; nt < 4; nt++) {
        int row = wn * 64 + nt * 16 + lr;
        int sl = (kk * 4 + hi) ^ (row & 7);
        bfr[nt] = *(const bf16x8*)(Bsb + cur * 8192 + row * 64 + sl * 8);
      }
      __builtin_amdgcn_s_setprio(1);
#pragma unroll
      for (int mt = 0; mt < 4; mt++)
#pragma unroll
        for (int nt = 0; nt < 4; nt++)
          acc[mt][nt] = mfma16(af[mt], bfr[nt], acc[mt][nt]);
      __builtin_amdgcn_s_setprio(0);
    }
    __syncthreads();
  }
#undef GSTAGE

#pragma unroll
  for (int mt = 0; mt < 4; mt++)
#pragma unroll
    for (int nt = 0; nt < 4; nt++)
#pragma unroll
      for (int r = 0; r < 4; r++) {
        int grow = m0 + wm * 64 + mt * 16 + 4 * hi + r;
        int gcol = n0 + wn * 64 + nt * 16 + lr;
        C[(size_t)grow * N + gcol] = acc[mt][nt][r] + bias[gcol];
      }
}

// ---------------- Flash attention v4 (accl — proven 81.3 us) ----------------
__global__ __launch_bounds__(512, 4) void k_attn(const bf16* __restrict__ Qh,
                                                 const bf16* __restrict__ Kh,
                                                 const bf16* __restrict__ Vt,
                                                 bf16* __restrict__ ctx) {
  __shared__ alignas(16) bf16 Ks[2][64 * 64];
  __shared__ alignas(16) bf16 Vs[2][64 * 64];
  int tid = threadIdx.x;
  int wave = tid >> 6, lane = tid & 63, hi2 = lane >> 5, l31 = lane & 31;
  int qt = blockIdx.x, h = blockIdx.y, b = blockIdx.z;
  int kv = h & 7;
  int q0 = qt * 256 + wave * 32;

  bf16x8 qf[4];
  {
    const float QSC = 0.125f * LOG2E;
    const bf16* qp = Qh + (size_t)(b * S_ + q0 + l31) * D_ + h * HD_ + hi2 * 8;
#pragma unroll
    for (int df = 0; df < 4; df++) {
      bf16x8 v = *(const bf16x8*)(qp + 16 * df);
#pragma unroll
      for (int j = 0; j < 8; j++) v[j] = (bf16)((float)v[j] * QSC);
      qf[df] = v;
    }
  }

  f32x16 o0, o1, accl;
#pragma unroll
  for (int i = 0; i < 16; i++) { o0[i] = 0.f; o1[i] = 0.f; accl[i] = 0.f; }
  bf16x8 ones;
#pragma unroll
  for (int j = 0; j < 8; j++) ones[j] = (bf16)1.0f;

  const bf16* Kg = Kh + (size_t)(b * S_) * KVD_ + kv * HD_;
  const bf16* Vg = Vt + (size_t)(b * KVH_ + kv) * HD_ * S_;

  int c_row = tid >> 3, c_slot = tid & 7;
  int c_dch = c_slot ^ (c_row & 7);

#define STAGE(buf, kt_)                                                        \
  do {                                                                         \
    gload_lds16(Kg + (size_t)((kt_) * 64 + c_row) * KVD_ + c_dch * 8,          \
                &Ks[buf][tid * 8]);                                            \
    gload_lds16(Vg + (size_t)c_row * S_ + (kt_) * 64 + c_dch * 8,              \
                &Vs[buf][tid * 8]);                                            \
  } while (0)

  STAGE(0, 0);
  __syncthreads();

  const int NT = S_ / 64;
  for (int kt = 0; kt < NT; kt++) {
    int cur = kt & 1;
    if (kt + 1 < NT) STAGE(cur ^ 1, kt + 1);

    const bf16* Kb = &Ks[cur][0];
    const bf16* Vb = &Vs[cur][0];

    f32x16 s0, s1;
#pragma unroll
    for (int i = 0; i < 16; i++) { s0[i] = 0.f; s1[i] = 0.f; }
    __builtin_amdgcn_s_setprio(1);
#pragma unroll
    for (int df = 0; df < 4; df++) {
      int ch = hi2 + 2 * df;
      int sl = (ch ^ (l31 & 7)) << 3;
      bf16x8 k0 = *(const bf16x8*)(Kb + l31 * 64 + sl);
      bf16x8 k1 = *(const bf16x8*)(Kb + (l31 + 32) * 64 + sl);
      s0 = mfma32(k0, qf[df], s0);
      s1 = mfma32(k1, qf[df], s1);
    }
    __builtin_amdgcn_s_setprio(0);

#pragma unroll
    for (int i = 0; i < 16; i++) s0[i] = __builtin_amdgcn_exp2f(s0[i]);
#pragma unroll
    for (int i = 0; i < 16; i++) s1[i] = __builtin_amdgcn_exp2f(s1[i]);

    unsigned Rk[2][4][2];
#pragma unroll
    for (int m = 0; m < 4; m++)
#pragma unroll
      for (int w = 0; w < 2; w++) {
        Rk[0][m][w] = pack_bf16(s0[4*m + 2*w], s0[4*m + 2*w + 1]);
        Rk[1][m][w] = pack_bf16(s1[4*m + 2*w], s1[4*m + 2*w + 1]);
      }
#pragma unroll
    for (int kf = 0; kf < 2; kf++)
#pragma unroll
      for (int kp = 0; kp < 2; kp++)
#pragma unroll
        for (int w = 0; w < 2; w++)
          asm volatile("v_permlane32_swap_b32 %0, %1"
                       : "+v"(Rk[kf][2*kp][w]), "+v"(Rk[kf][2*kp+1][w]));
    bf16x8 pf[4];
#pragma unroll
    for (int kfr = 0; kfr < 4; kfr++) {
      int kf = kfr >> 1, k2 = (kfr & 1) * 2;
      union { unsigned d[4]; bf16x8 v; } u;
      u.d[0] = Rk[kf][k2][0];     u.d[1] = Rk[kf][k2][1];
      u.d[2] = Rk[kf][k2 + 1][0]; u.d[3] = Rk[kf][k2 + 1][1];
      pf[kfr] = u.v;
    }

    __builtin_amdgcn_s_setprio(1);
#pragma unroll
    for (int kfr = 0; kfr < 4; kfr++) {
      int ch = hi2 + 2 * kfr;
      int sl = (ch ^ (l31 & 7)) << 3;
      bf16x8 v0 = *(const bf16x8*)(Vb + l31 * 64 + sl);
      bf16x8 v1 = *(const bf16x8*)(Vb + (l31 + 32) * 64 + sl);
      o0 = mfma32(pf[kfr], v0, o0);
      o1 = mfma32(pf[kfr], v1, o1);
      accl = mfma32(pf[kfr], ones, accl);
    }
    __builtin_amdgcn_s_setprio(0);
    __syncthreads();
  }
#undef STAGE

#pragma unroll
  for (int r = 0; r < 16; r++) {
    int rowq = (r & 3) + 8 * (r >> 2) + 4 * hi2;
    float inv = 1.f / accl[r];
    size_t base = (size_t)(b * S_ + q0 + rowq) * D_ + h * HD_;
    ctx[base + l31]      = (bf16)(o0[r] * inv);
    ctx[base + l31 + 32] = (bf16)(o1[r] * inv);
  }
}

// ---------------- host: 5 dispatches ----------------
extern "C" void kernel_launch(void* const* d_in, const int* in_sizes, int n_in,
                              void* d_out, int out_size, void* d_ws, size_t ws_size,
                              hipStream_t stream) {
  const float* q  = (const float*)d_in[0];
  const float* k  = (const float*)d_in[1];
  const float* v  = (const float*)d_in[2];
  const float* Wq = (const float*)d_in[4];
  const float* Wk = (const float*)d_in[5];
  const float* Wv = (const float*)d_in[6];
  const float* Wo = (const float*)d_in[7];
  const float* bo = (const float*)d_in[8];

  char* ws = (char*)d_ws;
  bf16*   WtO = (bf16*)(ws + 0);           //  8.39 MB
  bf16*   WtK = (bf16*)(ws + 8388608);     //  2.10 MB
  bf16*   WtV = (bf16*)(ws + 10485760);    //  2.10 MB
  bf16*   ctx = (bf16*)(ws + 16777216);    // 16.78 MB
  bf16*   WtQ = (bf16*)(ws + 33554432);    //  8.39 MB
  bf16*   Qh  = (bf16*)(ws + 41943040);    // 16.78 MB
  bf16*   Kh  = (bf16*)(ws + 58720256);    //  4.19 MB
  bf16*   Vt  = (bf16*)(ws + 62914560);    //  4.19 MB  [B][KVD][S]
  float2* tab = (float2*)(ws + 67108864);  //  0.52 MB  (end 67,633,152)

  k_prep<<<dim3(64, 64, 4), dim3(32, 8), 0, stream>>>(Wq, Wk, Wv, Wo,
                                                      WtQ, WtK, WtV, WtO, tab);
  k_gemm_q<<<dim3(D_/128, NROW_/128), 256, 0, stream>>>(q, WtQ, Qh, tab);
  k_gemm_kv<<<dim3(KVD_/128, NROW_/64, 2), 256, 0, stream>>>(k, v, WtK, WtV, Kh, Vt, tab);
  k_attn<<<dim3(S_/256, QH_, B_), 512, 0, stream>>>(Qh, Kh, Vt, ctx);
  k_gemm_o<<<dim3(D_/128, NROW_/128), 256, 0, stream>>>(ctx, WtO, (float*)d_out, bo);
}